// Round 2
// baseline (1281.961 us; speedup 1.0000x reference)
//
#include <hip/hip_runtime.h>
#include <math.h>

#define BB 2
#define TT 2048
#define EE 1024
#define HH 16
#define HDD 64
#define SBUF (BB*TT*EE)   // 4194304 floats per (B,T,E) buffer

// ---------------------------------------------------------------------------
// GEMM: C[m][n] = sum_k A[m][k] * W[n][k] + bias[n]   (i.e. A @ W^T + b)
// A: (4096, 1024), W: (1024, 1024) row-major. Tiles 64x64x32, 256 thr, 4x4.
// blockIdx.z selects one of up to 4 (W, bias, C) triples (fused QKVG pass).
// ---------------------------------------------------------------------------
__global__ __launch_bounds__(256)
void gemm_bias(const float* __restrict__ A,
               const float* __restrict__ W0, const float* __restrict__ W1,
               const float* __restrict__ W2, const float* __restrict__ W3,
               const float* __restrict__ b0, const float* __restrict__ b1,
               const float* __restrict__ b2, const float* __restrict__ b3,
               float* __restrict__ C0, float* __restrict__ C1,
               float* __restrict__ C2, float* __restrict__ C3)
{
    const float* W; const float* bias; float* C;
    switch (blockIdx.z) {
        case 0:  W = W0; bias = b0; C = C0; break;
        case 1:  W = W1; bias = b1; C = C1; break;
        case 2:  W = W2; bias = b2; C = C2; break;
        default: W = W3; bias = b3; C = C3; break;
    }
    __shared__ __align__(16) float As[32][68];  // [k][m]
    __shared__ __align__(16) float Ws[32][68];  // [k][n]
    const int bn  = blockIdx.x * 64;
    const int bm  = blockIdx.y * 64;
    const int tid = threadIdx.x;
    const int tx  = tid & 15, ty = tid >> 4;

    float acc[4][4] = {};
    for (int k0 = 0; k0 < EE; k0 += 32) {
        __syncthreads();
        #pragma unroll
        for (int i = 0; i < 8; ++i) {
            int idx = tid + 256*i;      // 0..2047
            int r = idx >> 5;           // 0..63  (m or n within tile)
            int c = idx & 31;           // 0..31  (k within tile)
            As[c][r] = A[(bm + r)*EE + k0 + c];
            Ws[c][r] = W[(bn + r)*EE + k0 + c];
        }
        __syncthreads();
        #pragma unroll
        for (int kk = 0; kk < 32; ++kk) {
            float4 a4 = *(const float4*)&As[kk][ty*4];
            float4 b4 = *(const float4*)&Ws[kk][tx*4];
            float av[4] = {a4.x, a4.y, a4.z, a4.w};
            float bv[4] = {b4.x, b4.y, b4.z, b4.w};
            #pragma unroll
            for (int i = 0; i < 4; ++i)
                #pragma unroll
                for (int j = 0; j < 4; ++j)
                    acc[i][j] += av[i] * bv[j];
        }
    }
    #pragma unroll
    for (int i = 0; i < 4; ++i) {
        int m = bm + ty*4 + i;
        #pragma unroll
        for (int j = 0; j < 4; ++j) {
            int n = bn + tx*4 + j;
            C[m*EE + n] = acc[i][j] + bias[n];
        }
    }
}

// ---------------------------------------------------------------------------
// RoPE (reference variant: element j uses freq index (j mod 32)).
// In-place on Q and K, layout (B,T,E) as (B,T,H,HD). blockIdx.z: 0->Q, 1->K.
// ---------------------------------------------------------------------------
__global__ __launch_bounds__(256)
void rope_kernel(float* __restrict__ Q, float* __restrict__ K)
{
    float* X = (blockIdx.z == 0) ? Q : K;
    int p = blockIdx.x * 256 + threadIdx.x;   // pair index in [0, B*T*E/2)
    int e_half = p & 511;                     // E/2 = 512
    int bt = p >> 9;
    int t  = bt & (TT - 1);
    int h  = e_half >> 5;                     // 32 pairs per head
    int i  = e_half & 31;
    int j  = 2*i;
    int base = bt*EE + h*HDD;
    float x0 = X[base + j];
    float x1 = X[base + j + 1];
    const float NEG_L2_10000_DIV32 = -13.28771237954945f / 32.f;  // -log2(10000)/32
    float fa = exp2f((float)( j      & 31) * NEG_L2_10000_DIV32);
    float fb = exp2f((float)((j + 1) & 31) * NEG_L2_10000_DIV32);
    float a0 = (float)t * fa;
    float a1 = (float)t * fb;
    X[base + j]     = x0*cosf(a0) - x1*sinf(a0);
    X[base + j + 1] = x1*cosf(a1) + x0*sinf(a1);
}

// ---------------------------------------------------------------------------
// Retention (reference is ANTI-causal): for query row m,
//   O[m] = sum_{n >= m} (Q_m . K_n / 8) * gamma^(n-m) * V[n]
// Tiles: 64 query rows per block, kv tiles n0 = m0 .. T-64.
// ---------------------------------------------------------------------------
__global__ __launch_bounds__(256)
void retention_kernel(const float* __restrict__ Q, const float* __restrict__ K,
                      const float* __restrict__ V, float* __restrict__ O)
{
    __shared__ __align__(16) float Qs [64][68];
    __shared__ __align__(16) float KSs[64][68];
    __shared__ __align__(16) float Vs [64][68];
    const int mt = blockIdx.x, h = blockIdx.y, b = blockIdx.z;
    const int m0 = mt * 64;
    const int tid = threadIdx.x;
    const int tx = tid & 15, ty = tid >> 4;
    const float gamma = 1.f - exp2f(-5.f - (float)h);
    const float l2g   = log2f(gamma);

    #pragma unroll
    for (int i = 0; i < 16; ++i) {
        int idx = tid + 256*i;        // 0..4095
        int r = idx >> 6, c = idx & 63;
        Qs[c][r] = Q[(b*TT + m0 + r)*EE + h*HDD + c];   // [k][r]
    }

    float o[4][4] = {};
    for (int n0 = m0; n0 < TT; n0 += 64) {
        __syncthreads();   // prev PV reads done before overwriting KSs/Vs
        #pragma unroll
        for (int i = 0; i < 16; ++i) {
            int idx = tid + 256*i;
            int r = idx >> 6, c = idx & 63;
            KSs[c][r] = K[(b*TT + n0 + r)*EE + h*HDD + c];  // [k][n]
            Vs [r][c] = V[(b*TT + n0 + r)*EE + h*HDD + c];  // [n][d]
        }
        __syncthreads();

        float s[4][4] = {};
        #pragma unroll
        for (int kk = 0; kk < 64; ++kk) {
            float4 q4 = *(const float4*)&Qs [kk][ty*4];
            float4 k4 = *(const float4*)&KSs[kk][tx*4];
            float qv[4] = {q4.x, q4.y, q4.z, q4.w};
            float kv[4] = {k4.x, k4.y, k4.z, k4.w};
            #pragma unroll
            for (int i = 0; i < 4; ++i)
                #pragma unroll
                for (int j = 0; j < 4; ++j)
                    s[i][j] += qv[i] * kv[j];
        }
        // anti-causal decay mask + 1/sqrt(HD) scale
        #pragma unroll
        for (int i = 0; i < 4; ++i) {
            int m = m0 + ty*4 + i;
            #pragma unroll
            for (int j = 0; j < 4; ++j) {
                int n = n0 + tx*4 + j;
                float w = (n >= m) ? 0.125f * exp2f(l2g * (float)(n - m)) : 0.f;
                s[i][j] *= w;
            }
        }
        __syncthreads();   // all QK^T reads of KSs done
        #pragma unroll
        for (int i = 0; i < 4; ++i) {
            float4 sv = make_float4(s[i][0], s[i][1], s[i][2], s[i][3]);
            *(float4*)&KSs[ty*4 + i][tx*4] = sv;    // S: [r][n]
        }
        __syncthreads();
        // PV: o[i][j] += sum_n S[r_i][n] * V[n][c_j]
        #pragma unroll
        for (int n = 0; n < 64; ++n) {
            float4 v4 = *(const float4*)&Vs[n][tx*4];
            float vv[4] = {v4.x, v4.y, v4.z, v4.w};
            #pragma unroll
            for (int i = 0; i < 4; ++i) {
                float sv = KSs[ty*4 + i][n];
                #pragma unroll
                for (int j = 0; j < 4; ++j)
                    o[i][j] += sv * vv[j];
            }
        }
    }
    #pragma unroll
    for (int i = 0; i < 4; ++i) {
        int m = m0 + ty*4 + i;
        #pragma unroll
        for (int j = 0; j < 4; ++j)
            O[(b*TT + m)*EE + h*HDD + tx*4 + j] = o[i][j];
    }
}

// ---------------------------------------------------------------------------
// GroupNorm stats: one block per (b,h), reduce mean/var over (HD*T)=131072.
// ---------------------------------------------------------------------------
__global__ __launch_bounds__(256)
void gn_stats(const float* __restrict__ R, float* __restrict__ stats)
{
    int bh = blockIdx.x;
    int b = bh >> 4, h = bh & 15;
    const float* base = R + (size_t)b*TT*EE + h*HDD;
    float s = 0.f, sq = 0.f;
    for (int idx = threadIdx.x; idx < TT*HDD; idx += 256) {
        int t = idx >> 6, d = idx & 63;
        float v = base[t*EE + d];
        s += v; sq += v*v;
    }
    #pragma unroll
    for (int off = 32; off; off >>= 1) {
        s  += __shfl_down(s,  off, 64);
        sq += __shfl_down(sq, off, 64);
    }
    __shared__ float ls[4], lq[4];
    int lane = threadIdx.x & 63, w = threadIdx.x >> 6;
    if (lane == 0) { ls[w] = s; lq[w] = sq; }
    __syncthreads();
    if (threadIdx.x == 0) {
        float S  = ls[0] + ls[1] + ls[2] + ls[3];
        float Sq = lq[0] + lq[1] + lq[2] + lq[3];
        const float inv = 1.f / (float)(TT*HDD);
        float mu  = S * inv;
        float var = Sq * inv - mu*mu;
        stats[2*bh]     = mu;
        stats[2*bh + 1] = rsqrtf(var + 1e-5f);
    }
}

// ---------------------------------------------------------------------------
// Z = silu(G) * ((R - mu) * rsigma * gn_w[e] + gn_b[e]),  written into G.
// ---------------------------------------------------------------------------
__global__ __launch_bounds__(256)
void zgate(float* __restrict__ G, const float* __restrict__ R,
           const float* __restrict__ stats,
           const float* __restrict__ gw, const float* __restrict__ gb)
{
    int i = blockIdx.x * 256 + threadIdx.x;   // [0, B*T*E)
    int e = i & (EE - 1);
    int b = i >> 21;                          // T*E = 2^21
    int bh = b*HH + (e >> 6);
    float mu = stats[2*bh], rs = stats[2*bh + 1];
    float g = G[i], r = R[i];
    float gate = g / (1.f + expf(-g));
    G[i] = gate * ((r - mu)*rs*gw[e] + gb[e]);
}

// ---------------------------------------------------------------------------
extern "C" void kernel_launch(void* const* d_in, const int* in_sizes, int n_in,
                              void* d_out, int out_size, void* d_ws, size_t ws_size,
                              hipStream_t stream)
{
    const float* x  = (const float*)d_in[0];
    const float* Wq = (const float*)d_in[1];
    const float* bq = (const float*)d_in[2];
    const float* Wk = (const float*)d_in[3];
    const float* bk = (const float*)d_in[4];
    const float* Wv = (const float*)d_in[5];
    const float* bv = (const float*)d_in[6];
    const float* Wg = (const float*)d_in[7];
    const float* bg = (const float*)d_in[8];
    const float* Wo = (const float*)d_in[9];
    const float* bo = (const float*)d_in[10];
    const float* gw = (const float*)d_in[11];
    const float* gb = (const float*)d_in[12];
    float* out = (float*)d_out;

    float* ws    = (float*)d_ws;              // needs ~84 MB
    float* Qb    = ws;
    float* Kb    = ws + (size_t)SBUF;
    float* Vb    = ws + 2*(size_t)SBUF;
    float* Gb    = ws + 3*(size_t)SBUF;
    float* Rb    = ws + 4*(size_t)SBUF;
    float* stats = ws + 5*(size_t)SBUF;       // 64 floats

    // 1) fused Q/K/V/G projections: x @ W^T + b
    gemm_bias<<<dim3(16, 64, 4), 256, 0, stream>>>(
        x, Wq, Wk, Wv, Wg, bq, bk, bv, bg, Qb, Kb, Vb, Gb);
    // 2) RoPE on Q and K (in place)
    rope_kernel<<<dim3(8192, 1, 2), 256, 0, stream>>>(Qb, Kb);
    // 3) retention core (anti-causal per reference)
    retention_kernel<<<dim3(32, 16, 2), 256, 0, stream>>>(Qb, Kb, Vb, Rb);
    // 4) group-norm stats per (b,h)
    gn_stats<<<32, 256, 0, stream>>>(Rb, stats);
    // 5) gate * norm  (into Gb)
    zgate<<<16384, 256, 0, stream>>>(Gb, Rb, stats, gw, gb);
    // 6) output projection: Z @ Wo^T + bo
    gemm_bias<<<dim3(16, 64, 1), 256, 0, stream>>>(
        Gb, Wo, Wo, Wo, Wo, bo, bo, bo, bo, out, out, out, out);
}

// Round 3
// 285.159 us; speedup vs baseline: 4.4956x; 4.4956x over previous
//
#include <hip/hip_runtime.h>
#include <math.h>

typedef unsigned short u16;
typedef __attribute__((ext_vector_type(8))) short short8;
typedef __attribute__((ext_vector_type(4))) float f32x4;

#define BB 2
#define TT 2048
#define EE 1024
#define HH 16
#define HDD 64

__device__ __forceinline__ float bf2f(u16 u){ union{unsigned i; float f;} v; v.i=((unsigned)u)<<16; return v.f; }
__device__ __forceinline__ u16 f2bf(float f){ union{float f; unsigned i;} v; v.f=f; return (u16)((v.i + 0x7fffu + ((v.i>>16)&1u))>>16); }

__device__ __forceinline__ void gload16(const void* g, void* l){
    __builtin_amdgcn_global_load_lds((const __attribute__((address_space(1))) void*)g,
                                     (__attribute__((address_space(3))) void*)l, 16, 0, 0);
}

// ---------------------------------------------------------------------------
// f32 -> bf16 conversion with GEMM chunk swizzle baked into global layout:
// within each row, 8-elem chunk ct stored at (ct&~3)|((ct&3)^((row>>1)&3)).
// ---------------------------------------------------------------------------
__global__ __launch_bounds__(256)
void cvt_swz(const float* __restrict__ s0, const float* __restrict__ s1,
             const float* __restrict__ s2, const float* __restrict__ s3,
             const float* __restrict__ s4, const float* __restrict__ s5,
             u16* __restrict__ d0, u16* __restrict__ d1, u16* __restrict__ d2,
             u16* __restrict__ d3, u16* __restrict__ d4, u16* __restrict__ d5)
{
    const float* S; u16* D; int nch;
    switch (blockIdx.z) {
        case 0: S=s0; D=d0; nch=4096*128; break;
        case 1: S=s1; D=d1; nch=1024*128; break;
        case 2: S=s2; D=d2; nch=1024*128; break;
        case 3: S=s3; D=d3; nch=1024*128; break;
        case 4: S=s4; D=d4; nch=1024*128; break;
        default:S=s5; D=d5; nch=1024*128; break;
    }
    int ci = blockIdx.x*256 + threadIdx.x;
    if (ci >= nch) return;
    int r = ci >> 7, c = ci & 127;
    int pc = (c & ~3) | ((c & 3) ^ ((r >> 1) & 3));
    const float4* sp = (const float4*)(S + (size_t)r*EE + c*8);
    float4 f0 = sp[0], f1 = sp[1];
    short8 ov; u16* o = (u16*)&ov;
    o[0]=f2bf(f0.x); o[1]=f2bf(f0.y); o[2]=f2bf(f0.z); o[3]=f2bf(f0.w);
    o[4]=f2bf(f1.x); o[5]=f2bf(f1.y); o[6]=f2bf(f1.z); o[7]=f2bf(f1.w);
    *(short8*)(D + (size_t)r*EE + pc*8) = ov;
}

// ---------------------------------------------------------------------------
// RoPE trig table: angle(t,f) = t * 10000^(-f/32), f in [0,32)
// ---------------------------------------------------------------------------
__global__ __launch_bounds__(256)
void trig_tab(float* __restrict__ ctab, float* __restrict__ stab)
{
    int idx = blockIdx.x*256 + threadIdx.x;   // 65536
    int t = idx >> 5, f = idx & 31;
    float ang = (float)t * exp2f(-(float)f * (13.287712379549449f/32.f));
    ctab[idx] = cosf(ang);
    stab[idx] = sinf(ang);
}

// ---------------------------------------------------------------------------
// Shared MFMA GEMM core: C(128x128) tile of A(4096x1024) @ W(1024x1024)^T.
// A and W stored bf16 with the cvt_swz chunk swizzle. 256 thr = 4 waves (2x2),
// wave tile 64x64 = 4x4 frags of 16x16, BK=32.
// ---------------------------------------------------------------------------
__device__ __forceinline__ void gemm_core(const u16* __restrict__ A, const u16* __restrict__ Bm,
                                          u16* As, u16* Bs, int bm, int bn, f32x4 (&acc)[4][4])
{
    const int tid = threadIdx.x;
    const int lane = tid & 63;
    const int g = lane >> 4, rl = lane & 15;
    const int w = tid >> 6, wr = w >> 1, wc = w & 1;
    for (int k0 = 0; k0 < EE; k0 += 32) {
        __syncthreads();
        {
            int cc = tid, r = cc >> 2, c = cc & 3;
            gload16(A  + (size_t)(bm + r)*EE + k0 + c*8, &As[cc*8]);
            gload16(Bm + (size_t)(bn + r)*EE + k0 + c*8, &Bs[cc*8]);
            cc = tid + 256; r = cc >> 2; c = cc & 3;
            gload16(A  + (size_t)(bm + r)*EE + k0 + c*8, &As[cc*8]);
            gload16(Bm + (size_t)(bn + r)*EE + k0 + c*8, &Bs[cc*8]);
        }
        __syncthreads();
        short8 a[4], b[4];
        #pragma unroll
        for (int i = 0; i < 4; ++i) {
            int m = wr*64 + i*16 + rl;
            a[i] = *(const short8*)&As[m*32 + ((g ^ ((m>>1)&3)) << 3)];
            int n = wc*64 + i*16 + rl;
            b[i] = *(const short8*)&Bs[n*32 + ((g ^ ((n>>1)&3)) << 3)];
        }
        #pragma unroll
        for (int i = 0; i < 4; ++i)
            #pragma unroll
            for (int j = 0; j < 4; ++j)
                acc[i][j] = __builtin_amdgcn_mfma_f32_16x16x32_bf16(a[i], b[j], acc[i][j], 0, 0, 0);
    }
}

// Fused Q/K/V/G projections. Q,K written with retention d-chunk swizzle
// (chunk p holds logical chunk p^(t&7)); V,G plain bf16.
__global__ __launch_bounds__(256)
void gemm_qkvg(const u16* __restrict__ A,
               const u16* __restrict__ W0, const u16* __restrict__ W1,
               const u16* __restrict__ W2, const u16* __restrict__ W3,
               const float* __restrict__ b0, const float* __restrict__ b1,
               const float* __restrict__ b2, const float* __restrict__ b3,
               u16* __restrict__ C0, u16* __restrict__ C1,
               u16* __restrict__ C2, u16* __restrict__ C3)
{
    __shared__ u16 As[128*32], Bs[128*32];
    const u16* W; const float* bias; u16* C; int swz;
    switch (blockIdx.z) {
        case 0: W=W0; bias=b0; C=C0; swz=1; break;
        case 1: W=W1; bias=b1; C=C1; swz=1; break;
        case 2: W=W2; bias=b2; C=C2; swz=0; break;
        default:W=W3; bias=b3; C=C3; swz=0; break;
    }
    int bm = blockIdx.y*128, bn = blockIdx.x*128;
    f32x4 acc[4][4] = {};
    gemm_core(A, W, As, Bs, bm, bn, acc);
    const int lane = threadIdx.x & 63, g = lane>>4, rl = lane&15;
    const int w = threadIdx.x >> 6, wr = w>>1, wc = w&1;
    float bj[4];
    #pragma unroll
    for (int j = 0; j < 4; ++j) bj[j] = bias[bn + wc*64 + j*16 + rl];
    #pragma unroll
    for (int i = 0; i < 4; ++i)
      #pragma unroll
      for (int rr = 0; rr < 4; ++rr) {
        int m = bm + wr*64 + i*16 + g*4 + rr;
        #pragma unroll
        for (int j = 0; j < 4; ++j) {
            int n = bn + wc*64 + j*16 + rl;
            float v = acc[i][j][rr] + bj[j];
            int col = swz ? ((n & ~63) | ((((n>>3)&7) ^ (m&7)) << 3) | (n & 7)) : n;
            C[(size_t)m*EE + col] = f2bf(v);
        }
      }
}

// Output projection: Z @ Wo^T + bo -> f32
__global__ __launch_bounds__(256)
void gemm_out(const u16* __restrict__ A, const u16* __restrict__ W,
              const float* __restrict__ bias, float* __restrict__ C)
{
    __shared__ u16 As[128*32], Bs[128*32];
    int bm = blockIdx.y*128, bn = blockIdx.x*128;
    f32x4 acc[4][4] = {};
    gemm_core(A, W, As, Bs, bm, bn, acc);
    const int lane = threadIdx.x & 63, g = lane>>4, rl = lane&15;
    const int w = threadIdx.x >> 6, wr = w>>1, wc = w&1;
    float bj[4];
    #pragma unroll
    for (int j = 0; j < 4; ++j) bj[j] = bias[bn + wc*64 + j*16 + rl];
    #pragma unroll
    for (int i = 0; i < 4; ++i)
      #pragma unroll
      for (int rr = 0; rr < 4; ++rr) {
        int m = bm + wr*64 + i*16 + g*4 + rr;
        #pragma unroll
        for (int j = 0; j < 4; ++j) {
            int n = bn + wc*64 + j*16 + rl;
            C[(size_t)m*EE + n] = acc[i][j][rr] + bj[j];
        }
      }
}

// ---------------------------------------------------------------------------
// RoPE in place on swizzled bf16 Q/K. Stored chunk p of (t,h) holds logical
// d-chunk p^(t&7); element j uses table freq (j&31).
// ---------------------------------------------------------------------------
__global__ __launch_bounds__(256)
void rope_swz(u16* __restrict__ Q, u16* __restrict__ K,
              const float* __restrict__ ctab, const float* __restrict__ stab)
{
    u16* X = blockIdx.z ? K : Q;
    int ci = blockIdx.x*256 + threadIdx.x;     // 0..524287
    int row = ci >> 7;                         // b*T + t
    int t = row & (TT-1);
    int c = ci & 127, h = c >> 3, p = c & 7;
    int d0 = (p ^ (t & 7)) << 3;               // logical element base in head
    u16* ptr = X + (size_t)row*EE + h*HDD + p*8;
    short8 xv = *(short8*)ptr;
    u16* xu = (u16*)&xv;
    const float* cr = ctab + t*32;
    const float* sr = stab + t*32;
    short8 ov; u16* o = (u16*)&ov;
    #pragma unroll
    for (int q = 0; q < 4; ++q) {
        int j0 = d0 + 2*q;
        float xe = bf2f(xu[2*q]), xo = bf2f(xu[2*q+1]);
        float c0 = cr[j0 & 31],     s0 = sr[j0 & 31];
        float c1 = cr[(j0+1) & 31], s1 = sr[(j0+1) & 31];
        o[2*q]   = f2bf(xe*c0 - xo*s0);
        o[2*q+1] = f2bf(xo*c1 + xe*s1);
    }
    *(short8*)ptr = ov;
}

// ---------------------------------------------------------------------------
// V -> VT [b][h][d][t], with t-chunk swizzle (pos p holds logical p^(d&7)).
// ---------------------------------------------------------------------------
__global__ __launch_bounds__(256)
void transV(const u16* __restrict__ V, u16* __restrict__ VT)
{
    __shared__ u16 ts[64*64];
    int t0 = blockIdx.x * 64, h = blockIdx.y, b = blockIdx.z;
    int tid = threadIdx.x;
    #pragma unroll
    for (int rr = 0; rr < 2; ++rr) {
        int cc = tid + rr*256;
        int r = cc >> 3, c = cc & 7;
        short8 v = *(const short8*)(V + (size_t)(b*TT + t0 + r)*EE + h*HDD + c*8);
        *(short8*)&ts[r*64 + ((c ^ (r & 7)) << 3)] = v;
    }
    __syncthreads();
    #pragma unroll
    for (int rr = 0; rr < 2; ++rr) {
        int oc = tid + rr*256;
        int d = oc & 63, tp = oc >> 6;       // d 0..63, tp 0..7 over 2 rounds
        short8 ov; u16* o = (u16*)&ov;
        #pragma unroll
        for (int e = 0; e < 8; ++e) {
            int t = tp*8 + e;
            o[e] = ts[t*64 + (((d>>3) ^ (t & 7)) << 3) + (d & 7)];
        }
        int ptp = tp ^ (d & 7);
        *(short8*)(VT + ((size_t)((b*HH + h)*HDD + d))*TT + t0 + ptp*8) = ov;
    }
}

// ---------------------------------------------------------------------------
// Retention core (anti-causal): O[m] = sum_{n>=m} (Q_m.K_n/8) g^(n-m) V[n].
// 64 q-rows/block, 4 waves each own 16 rows. QK^T and PV via MFMA; S goes
// through XOR-swizzled per-wave LDS rows.
// ---------------------------------------------------------------------------
__global__ __launch_bounds__(256)
void retention_mfma(const u16* __restrict__ Q, const u16* __restrict__ K,
                    const u16* __restrict__ VT, float* __restrict__ R)
{
    __shared__ u16 Qs[64*64], Ks[64*64], Vs[64*64], Ss[64*64];
    const int tid = threadIdx.x, w = tid >> 6, lane = tid & 63;
    const int g = lane >> 4, rl = lane & 15;
    const int m0 = blockIdx.x * 64, h = blockIdx.y, b = blockIdx.z;
    const float l2g = log2f(1.f - exp2f(-5.f - (float)h));

    {
        int cc = tid, r = cc >> 3, c = cc & 7;
        gload16(Q + (size_t)(b*TT + m0 + r)*EE + h*HDD + c*8, &Qs[cc*8]);
        cc = tid + 256; r = cc >> 3; c = cc & 7;
        gload16(Q + (size_t)(b*TT + m0 + r)*EE + h*HDD + c*8, &Qs[cc*8]);
    }

    short8 qf[2];
    f32x4 oacc[4] = {};
    const int mr = w*16 + rl;
    for (int n0 = m0; n0 < TT; n0 += 64) {
        __syncthreads();
        {
            int cc = tid, r = cc >> 3, c = cc & 7;
            gload16(K  + (size_t)(b*TT + n0 + r)*EE + h*HDD + c*8, &Ks[cc*8]);
            gload16(VT + ((size_t)((b*HH + h)*HDD + r))*TT + n0 + c*8, &Vs[cc*8]);
            cc = tid + 256; r = cc >> 3; c = cc & 7;
            gload16(K  + (size_t)(b*TT + n0 + r)*EE + h*HDD + c*8, &Ks[cc*8]);
            gload16(VT + ((size_t)((b*HH + h)*HDD + r))*TT + n0 + c*8, &Vs[cc*8]);
        }
        __syncthreads();
        if (n0 == m0) {
            qf[0] = *(const short8*)&Qs[mr*64 + ((g ^ (rl & 7)) << 3)];
            qf[1] = *(const short8*)&Qs[mr*64 + (((4+g) ^ (rl & 7)) << 3)];
        }
        f32x4 sacc[4] = {};
        #pragma unroll
        for (int j = 0; j < 4; ++j) {
            int n = j*16 + rl;
            short8 kf0 = *(const short8*)&Ks[n*64 + ((g ^ (n & 7)) << 3)];
            short8 kf1 = *(const short8*)&Ks[n*64 + (((4+g) ^ (n & 7)) << 3)];
            sacc[j] = __builtin_amdgcn_mfma_f32_16x16x32_bf16(qf[0], kf0, sacc[j], 0, 0, 0);
            sacc[j] = __builtin_amdgcn_mfma_f32_16x16x32_bf16(qf[1], kf1, sacc[j], 0, 0, 0);
        }
        // decay mask + scale, write S to wave-private swizzled LDS rows
        #pragma unroll
        for (int j = 0; j < 4; ++j) {
            int nl = j*16 + rl;
            int n_g = n0 + nl;
            #pragma unroll
            for (int rr = 0; rr < 4; ++rr) {
                int ml = w*16 + g*4 + rr;
                int diff = n_g - (m0 + ml);
                float sv = (diff >= 0) ? sacc[j][rr]*0.125f*exp2f(l2g*(float)diff) : 0.f;
                Ss[ml*64 + (((nl>>3) ^ (ml & 7)) << 3) + (nl & 7)] = f2bf(sv);
            }
        }
        asm volatile("s_waitcnt lgkmcnt(0)" ::: "memory");  // wave-local W->R ordering
        // PV
        #pragma unroll
        for (int s = 0; s < 2; ++s) {
            short8 sf = *(const short8*)&Ss[mr*64 + (((s*4 + g) ^ (rl & 7)) << 3)];
            #pragma unroll
            for (int j = 0; j < 4; ++j) {
                int d = j*16 + rl;
                short8 vf = *(const short8*)&Vs[d*64 + (((s*4 + g) ^ (d & 7)) << 3)];
                oacc[j] = __builtin_amdgcn_mfma_f32_16x16x32_bf16(sf, vf, oacc[j], 0, 0, 0);
            }
        }
    }
    #pragma unroll
    for (int j = 0; j < 4; ++j)
        #pragma unroll
        for (int rr = 0; rr < 4; ++rr) {
            int m_g = m0 + w*16 + g*4 + rr;
            R[(size_t)(b*TT + m_g)*EE + h*HDD + j*16 + rl] = oacc[j][rr];
        }
}

// ---------------------------------------------------------------------------
// GroupNorm: 512-block partial sums then finalize.
// ---------------------------------------------------------------------------
__global__ __launch_bounds__(256)
void gn_partial(const float* __restrict__ R, float* __restrict__ part)
{
    int bid = blockIdx.x;              // 512
    int bh = bid >> 4, seg = bid & 15;
    int b = bh >> 4, h = bh & 15;
    const float* base = R + (size_t)(b*TT + seg*128)*EE + h*HDD;
    float s = 0.f, sq = 0.f;
    #pragma unroll
    for (int k = 0; k < 8; ++k) {
        int i4 = threadIdx.x + 256*k;  // 0..2047 float4s
        int t = i4 >> 4, dq = i4 & 15;
        float4 v = *(const float4*)(base + (size_t)t*EE + dq*4);
        s  += v.x + v.y + v.z + v.w;
        sq += v.x*v.x + v.y*v.y + v.z*v.z + v.w*v.w;
    }
    #pragma unroll
    for (int off = 32; off; off >>= 1) { s += __shfl_down(s, off, 64); sq += __shfl_down(sq, off, 64); }
    __shared__ float ls[4], lq[4];
    int lane = threadIdx.x & 63, wv = threadIdx.x >> 6;
    if (lane == 0) { ls[wv] = s; lq[wv] = sq; }
    __syncthreads();
    if (threadIdx.x == 0) {
        part[2*bid]   = ls[0]+ls[1]+ls[2]+ls[3];
        part[2*bid+1] = lq[0]+lq[1]+lq[2]+lq[3];
    }
}

__global__ void gn_finalize(const float* __restrict__ part, float* __restrict__ stats)
{
    int bh = threadIdx.x;
    if (bh < 32) {
        float s = 0.f, sq = 0.f;
        #pragma unroll
        for (int k = 0; k < 16; ++k) { s += part[2*(bh*16+k)]; sq += part[2*(bh*16+k)+1]; }
        const float inv = 1.f / (float)(TT*HDD);
        float mu = s * inv;
        float var = sq * inv - mu*mu;
        stats[2*bh]   = mu;
        stats[2*bh+1] = rsqrtf(var + 1e-5f);
    }
}

// ---------------------------------------------------------------------------
// Z = silu(G) * groupnorm(R); written bf16 with GEMM-A chunk swizzle.
// ---------------------------------------------------------------------------
__global__ __launch_bounds__(256)
void zgate(const u16* __restrict__ G, const float* __restrict__ R,
           const float* __restrict__ stats, const float* __restrict__ gw,
           const float* __restrict__ gb, u16* __restrict__ Z)
{
    int ci = blockIdx.x*256 + threadIdx.x;   // 524288 chunks
    int row = ci >> 7;                       // b*T + t
    int c = ci & 127;
    int e0 = c*8;
    int b = row >> 11;
    int bh = b*HH + (e0 >> 6);
    float mu = stats[2*bh], rs = stats[2*bh+1];
    short8 gv = *(const short8*)(G + (size_t)row*EE + e0);
    const u16* gu = (const u16*)&gv;
    const float* rp = R + (size_t)row*EE + e0;
    float4 r0 = *(const float4*)rp, r1 = *(const float4*)(rp+4);
    float rr[8] = {r0.x,r0.y,r0.z,r0.w,r1.x,r1.y,r1.z,r1.w};
    short8 ov; u16* o = (u16*)&ov;
    #pragma unroll
    for (int q = 0; q < 8; ++q) {
        float gvf = bf2f(gu[q]);
        float gate = gvf / (1.f + __expf(-gvf));
        float nv = (rr[q] - mu)*rs*gw[e0+q] + gb[e0+q];
        o[q] = f2bf(gate*nv);
    }
    int pc = (c & ~3) | ((c & 3) ^ ((row >> 1) & 3));
    *(short8*)(Z + (size_t)row*EE + pc*8) = ov;
}

// ---------------------------------------------------------------------------
extern "C" void kernel_launch(void* const* d_in, const int* in_sizes, int n_in,
                              void* d_out, int out_size, void* d_ws, size_t ws_size,
                              hipStream_t stream)
{
    const float* x  = (const float*)d_in[0];
    const float* Wq = (const float*)d_in[1];
    const float* bq = (const float*)d_in[2];
    const float* Wk = (const float*)d_in[3];
    const float* bk = (const float*)d_in[4];
    const float* Wv = (const float*)d_in[5];
    const float* bv = (const float*)d_in[6];
    const float* Wg = (const float*)d_in[7];
    const float* bg = (const float*)d_in[8];
    const float* Wo = (const float*)d_in[9];
    const float* bo = (const float*)d_in[10];
    const float* gw = (const float*)d_in[11];
    const float* gb = (const float*)d_in[12];
    float* out = (float*)d_out;

    char* p = (char*)d_ws;
    u16* xb  = (u16*)p;              p += (size_t)8<<20;   // 8MB; reused as Zb
    u16* Wqb = (u16*)p;              p += (size_t)2<<20;
    u16* Wkb = (u16*)p;              p += (size_t)2<<20;
    u16* Wvb = (u16*)p;              p += (size_t)2<<20;
    u16* Wgb = (u16*)p;              p += (size_t)2<<20;
    u16* Wob = (u16*)p;              p += (size_t)2<<20;
    u16* Qb  = (u16*)p;              p += (size_t)8<<20;
    u16* Kb  = (u16*)p;              p += (size_t)8<<20;
    u16* Vb  = (u16*)p;              p += (size_t)8<<20;
    u16* Gb  = (u16*)p;              p += (size_t)8<<20;
    u16* VTb = (u16*)p;              p += (size_t)8<<20;
    float* Rb    = (float*)p;        p += (size_t)16<<20;
    float* part  = (float*)p;        p += 4096;
    float* stats = (float*)p;        p += 256;
    float* ctab  = (float*)p;        p += (size_t)65536*4;
    float* stab  = (float*)p;        p += (size_t)65536*4;
    u16* Zb = xb;   // x dead after QKVG projections

    // 1) convert inputs to bf16 (GEMM chunk-swizzled) + trig table
    cvt_swz<<<dim3(2048,1,6), 256, 0, stream>>>(x, Wq, Wk, Wv, Wg, Wo,
                                                xb, Wqb, Wkb, Wvb, Wgb, Wob);
    trig_tab<<<256, 256, 0, stream>>>(ctab, stab);
    // 2) fused QKVG projections (MFMA)
    gemm_qkvg<<<dim3(8,32,4), 256, 0, stream>>>(xb, Wqb, Wkb, Wvb, Wgb,
                                                bq, bk, bv, bg, Qb, Kb, Vb, Gb);
    // 3) RoPE on Q,K
    rope_swz<<<dim3(2048,1,2), 256, 0, stream>>>(Qb, Kb, ctab, stab);
    // 4) V transpose for PV B-operand
    transV<<<dim3(32,16,2), 256, 0, stream>>>(Vb, VTb);
    // 5) retention core
    retention_mfma<<<dim3(32,16,2), 256, 0, stream>>>(Qb, Kb, VTb, Rb);
    // 6) group-norm stats
    gn_partial<<<512, 256, 0, stream>>>(Rb, part);
    gn_finalize<<<1, 64, 0, stream>>>(part, stats);
    // 7) gate * norm -> Z (bf16, GEMM-swizzled)
    zgate<<<2048, 256, 0, stream>>>(Gb, Rb, stats, gw, gb, Zb);
    // 8) output projection
    gemm_out<<<dim3(8,32,1), 256, 0, stream>>>(Zb, Wob, bo, out);
}

// Round 4
// 230.373 us; speedup vs baseline: 5.5647x; 1.2378x over previous
//
#include <hip/hip_runtime.h>
#include <math.h>

typedef unsigned short u16;
typedef unsigned int u32;
typedef __attribute__((ext_vector_type(8))) short short8;
typedef __attribute__((ext_vector_type(4))) float f32x4;

#define BB 2
#define TT 2048
#define EE 1024
#define HH 16
#define HDD 64
#define NC 32
#define CS 64

__device__ __forceinline__ float bf2f(u16 u){ union{unsigned i; float f;} v; v.i=((unsigned)u)<<16; return v.f; }
__device__ __forceinline__ u16 f2bf(float f){ union{float f; unsigned i;} v; v.f=f; return (u16)((v.i + 0x7fffu + ((v.i>>16)&1u))>>16); }

__device__ __forceinline__ void gload16(const void* g, void* l){
    __builtin_amdgcn_global_load_lds((const __attribute__((address_space(1))) void*)g,
                                     (__attribute__((address_space(3))) void*)l, 16, 0, 0);
}

// ---------------------------------------------------------------------------
// f32 -> bf16 conversion with GEMM chunk swizzle baked into global layout.
// ---------------------------------------------------------------------------
__global__ __launch_bounds__(256)
void cvt_swz(const float* __restrict__ s0, const float* __restrict__ s1,
             const float* __restrict__ s2, const float* __restrict__ s3,
             const float* __restrict__ s4, const float* __restrict__ s5,
             u16* __restrict__ d0, u16* __restrict__ d1, u16* __restrict__ d2,
             u16* __restrict__ d3, u16* __restrict__ d4, u16* __restrict__ d5)
{
    const float* S; u16* D; int nch;
    switch (blockIdx.z) {
        case 0: S=s0; D=d0; nch=4096*128; break;
        case 1: S=s1; D=d1; nch=1024*128; break;
        case 2: S=s2; D=d2; nch=1024*128; break;
        case 3: S=s3; D=d3; nch=1024*128; break;
        case 4: S=s4; D=d4; nch=1024*128; break;
        default:S=s5; D=d5; nch=1024*128; break;
    }
    int ci = blockIdx.x*256 + threadIdx.x;
    if (ci >= nch) return;
    int r = ci >> 7, c = ci & 127;
    int pc = (c & ~3) | ((c & 3) ^ ((r >> 1) & 3));
    const float4* sp = (const float4*)(S + (size_t)r*EE + c*8);
    float4 f0 = sp[0], f1 = sp[1];
    short8 ov; u16* o = (u16*)&ov;
    o[0]=f2bf(f0.x); o[1]=f2bf(f0.y); o[2]=f2bf(f0.z); o[3]=f2bf(f0.w);
    o[4]=f2bf(f1.x); o[5]=f2bf(f1.y); o[6]=f2bf(f1.z); o[7]=f2bf(f1.w);
    *(short8*)(D + (size_t)r*EE + pc*8) = ov;
}

// ---------------------------------------------------------------------------
__global__ __launch_bounds__(256)
void trig_tab(float* __restrict__ ctab, float* __restrict__ stab)
{
    int idx = blockIdx.x*256 + threadIdx.x;   // 65536
    int t = idx >> 5, f = idx & 31;
    float ang = (float)t * exp2f(-(float)f * (13.287712379549449f/32.f));
    ctab[idx] = cosf(ang);
    stab[idx] = sinf(ang);
}

// ---------------------------------------------------------------------------
// MFMA GEMM core (128x128 tile, BK=32), A/W chunk-swizzled bf16.
// ---------------------------------------------------------------------------
__device__ __forceinline__ void gemm_core(const u16* __restrict__ A, const u16* __restrict__ Bm,
                                          u16* As, u16* Bs, int bm, int bn, f32x4 (&acc)[4][4])
{
    const int tid = threadIdx.x;
    const int lane = tid & 63;
    const int g = lane >> 4, rl = lane & 15;
    const int w = tid >> 6, wr = w >> 1, wc = w & 1;
    for (int k0 = 0; k0 < EE; k0 += 32) {
        __syncthreads();
        {
            int cc = tid, r = cc >> 2, c = cc & 3;
            gload16(A  + (size_t)(bm + r)*EE + k0 + c*8, &As[cc*8]);
            gload16(Bm + (size_t)(bn + r)*EE + k0 + c*8, &Bs[cc*8]);
            cc = tid + 256; r = cc >> 2; c = cc & 3;
            gload16(A  + (size_t)(bm + r)*EE + k0 + c*8, &As[cc*8]);
            gload16(Bm + (size_t)(bn + r)*EE + k0 + c*8, &Bs[cc*8]);
        }
        __syncthreads();
        short8 a[4], b[4];
        #pragma unroll
        for (int i = 0; i < 4; ++i) {
            int m = wr*64 + i*16 + rl;
            a[i] = *(const short8*)&As[m*32 + ((g ^ ((m>>1)&3)) << 3)];
            int n = wc*64 + i*16 + rl;
            b[i] = *(const short8*)&Bs[n*32 + ((g ^ ((n>>1)&3)) << 3)];
        }
        #pragma unroll
        for (int i = 0; i < 4; ++i)
            #pragma unroll
            for (int j = 0; j < 4; ++j)
                acc[i][j] = __builtin_amdgcn_mfma_f32_16x16x32_bf16(a[i], b[j], acc[i][j], 0, 0, 0);
    }
}

__global__ __launch_bounds__(256)
void gemm_qkvg(const u16* __restrict__ A,
               const u16* __restrict__ W0, const u16* __restrict__ W1,
               const u16* __restrict__ W2, const u16* __restrict__ W3,
               const float* __restrict__ b0, const float* __restrict__ b1,
               const float* __restrict__ b2, const float* __restrict__ b3,
               u16* __restrict__ C0, u16* __restrict__ C1,
               u16* __restrict__ C2, u16* __restrict__ C3)
{
    __shared__ u16 As[128*32], Bs[128*32];
    const u16* W; const float* bias; u16* C; int swz;
    switch (blockIdx.z) {
        case 0: W=W0; bias=b0; C=C0; swz=1; break;
        case 1: W=W1; bias=b1; C=C1; swz=1; break;
        case 2: W=W2; bias=b2; C=C2; swz=0; break;
        default:W=W3; bias=b3; C=C3; swz=0; break;
    }
    int bm = blockIdx.y*128, bn = blockIdx.x*128;
    f32x4 acc[4][4] = {};
    gemm_core(A, W, As, Bs, bm, bn, acc);
    const int lane = threadIdx.x & 63, g = lane>>4, rl = lane&15;
    const int w = threadIdx.x >> 6, wr = w>>1, wc = w&1;
    float bj[4];
    #pragma unroll
    for (int j = 0; j < 4; ++j) bj[j] = bias[bn + wc*64 + j*16 + rl];
    #pragma unroll
    for (int i = 0; i < 4; ++i)
      #pragma unroll
      for (int rr = 0; rr < 4; ++rr) {
        int m = bm + wr*64 + i*16 + g*4 + rr;
        #pragma unroll
        for (int j = 0; j < 4; ++j) {
            int n = bn + wc*64 + j*16 + rl;
            float v = acc[i][j][rr] + bj[j];
            int col = swz ? ((n & ~63) | ((((n>>3)&7) ^ (m&7)) << 3) | (n & 7)) : n;
            C[(size_t)m*EE + col] = f2bf(v);
        }
      }
}

__global__ __launch_bounds__(256)
void gemm_out(const u16* __restrict__ A, const u16* __restrict__ W,
              const float* __restrict__ bias, float* __restrict__ C)
{
    __shared__ u16 As[128*32], Bs[128*32];
    int bm = blockIdx.y*128, bn = blockIdx.x*128;
    f32x4 acc[4][4] = {};
    gemm_core(A, W, As, Bs, bm, bn, acc);
    const int lane = threadIdx.x & 63, g = lane>>4, rl = lane&15;
    const int w = threadIdx.x >> 6, wr = w>>1, wc = w&1;
    float bj[4];
    #pragma unroll
    for (int j = 0; j < 4; ++j) bj[j] = bias[bn + wc*64 + j*16 + rl];
    #pragma unroll
    for (int i = 0; i < 4; ++i)
      #pragma unroll
      for (int rr = 0; rr < 4; ++rr) {
        int m = bm + wr*64 + i*16 + g*4 + rr;
        #pragma unroll
        for (int j = 0; j < 4; ++j) {
            int n = bn + wc*64 + j*16 + rl;
            C[(size_t)m*EE + n] = acc[i][j][rr] + bj[j];
        }
      }
}

// ---------------------------------------------------------------------------
// RoPE in place on d-chunk-swizzled bf16 Q/K.
// ---------------------------------------------------------------------------
__global__ __launch_bounds__(256)
void rope_swz(u16* __restrict__ Q, u16* __restrict__ K,
              const float* __restrict__ ctab, const float* __restrict__ stab)
{
    u16* X = blockIdx.z ? K : Q;
    int ci = blockIdx.x*256 + threadIdx.x;
    int row = ci >> 7;
    int t = row & (TT-1);
    int c = ci & 127, h = c >> 3, p = c & 7;
    int d0 = (p ^ (t & 7)) << 3;
    u16* ptr = X + (size_t)row*EE + h*HDD + p*8;
    short8 xv = *(short8*)ptr;
    u16* xu = (u16*)&xv;
    const float* cr = ctab + t*32;
    const float* sr = stab + t*32;
    short8 ov; u16* o = (u16*)&ov;
    #pragma unroll
    for (int q = 0; q < 4; ++q) {
        int j0 = d0 + 2*q;
        float xe = bf2f(xu[2*q]), xo = bf2f(xu[2*q+1]);
        float c0 = cr[j0 & 31],     s0 = sr[j0 & 31];
        float c1 = cr[(j0+1) & 31], s1 = sr[(j0+1) & 31];
        o[2*q]   = f2bf(xe*c0 - xo*s0);
        o[2*q+1] = f2bf(xo*c1 + xe*s1);
    }
    *(short8*)ptr = ov;
}

// ---------------------------------------------------------------------------
// V -> VT [b][h][d][t] with t-chunk swizzle (pos p holds logical p^(d&7)).
// ---------------------------------------------------------------------------
__global__ __launch_bounds__(256)
void transV(const u16* __restrict__ V, u16* __restrict__ VT)
{
    __shared__ u16 ts[64*64];
    int t0 = blockIdx.x * 64, h = blockIdx.y, b = blockIdx.z;
    int tid = threadIdx.x;
    #pragma unroll
    for (int rr = 0; rr < 2; ++rr) {
        int cc = tid + rr*256;
        int r = cc >> 3, c = cc & 7;
        short8 v = *(const short8*)(V + (size_t)(b*TT + t0 + r)*EE + h*HDD + c*8);
        *(short8*)&ts[r*64 + ((c ^ (r & 7)) << 3)] = v;
    }
    __syncthreads();
    #pragma unroll
    for (int rr = 0; rr < 2; ++rr) {
        int oc = tid + rr*256;
        int d = oc & 63, tp = oc >> 6;
        short8 ov; u16* o = (u16*)&ov;
        #pragma unroll
        for (int e = 0; e < 8; ++e) {
            int t = tp*8 + e;
            o[e] = ts[t*64 + (((d>>3) ^ (t & 7)) << 3) + (d & 7)];
        }
        int ptp = tp ^ (d & 7);
        *(short8*)(VT + ((size_t)((b*HH + h)*HDD + d))*TT + t0 + ptp*8) = ov;
    }
}

// ---------------------------------------------------------------------------
// K (d-chunk-swizzled, post-RoPE) -> KT [b][h][d][t], scaled by gamma^(t&63),
// with the same t-chunk swizzle as VT.
// ---------------------------------------------------------------------------
__global__ __launch_bounds__(256)
void transK(const u16* __restrict__ K, u16* __restrict__ KT)
{
    __shared__ u16 ts[64*64];
    int t0 = blockIdx.x * 64, h = blockIdx.y, b = blockIdx.z;
    int tid = threadIdx.x;
    const float l2g = log2f(1.f - exp2f(-5.f - (float)h));
    #pragma unroll
    for (int rr = 0; rr < 2; ++rr) {
        int cc = tid + rr*256;
        int r = cc >> 3, c = cc & 7;           // c = STORED chunk = logical^(r&7)
        short8 v = *(const short8*)(K + (size_t)(b*TT + t0 + r)*EE + h*HDD + c*8);
        *(short8*)&ts[r*64 + (c << 3)] = v;    // lands at logical^(r&7) — transV convention
    }
    __syncthreads();
    #pragma unroll
    for (int rr = 0; rr < 2; ++rr) {
        int oc = tid + rr*256;
        int d = oc & 63, tp = oc >> 6;
        short8 ov; u16* o = (u16*)&ov;
        #pragma unroll
        for (int e = 0; e < 8; ++e) {
            int t = tp*8 + e;
            float val = bf2f(ts[t*64 + (((d>>3) ^ (t & 7)) << 3) + (d & 7)]);
            o[e] = f2bf(val * exp2f(l2g * (float)t));
        }
        int ptp = tp ^ (d & 7);
        *(short8*)(KT + ((size_t)((b*HH + h)*HDD + d))*TT + t0 + ptp*8) = ov;
    }
}

// ---------------------------------------------------------------------------
// Per-chunk state: Tt[c][d2][d1] = sum_n V[n][d2] * K[n][d1]*gamma^n̂  (f32).
// ---------------------------------------------------------------------------
__global__ __launch_bounds__(256)
void chunk_state(const u16* __restrict__ KT, const u16* __restrict__ VT,
                 float* __restrict__ Tb)
{
    __shared__ u16 Ks[64*64], Vs[64*64];
    const int tid = threadIdx.x, w = tid >> 6, lane = tid & 63;
    const int g = lane >> 4, rl = lane & 15;
    const int c = blockIdx.x, h = blockIdx.y, b = blockIdx.z;
    const int t0 = c*64;
    const size_t rowb = (size_t)((b*HH + h)*HDD);
    {
        int cc = tid, r = cc >> 3, ch = cc & 7;
        gload16(KT + (rowb + r)*TT + t0 + ch*8, &Ks[cc*8]);
        gload16(VT + (rowb + r)*TT + t0 + ch*8, &Vs[cc*8]);
        cc = tid + 256; r = cc >> 3; ch = cc & 7;
        gload16(KT + (rowb + r)*TT + t0 + ch*8, &Ks[cc*8]);
        gload16(VT + (rowb + r)*TT + t0 + ch*8, &Vs[cc*8]);
    }
    __syncthreads();
    int d2r = w*16 + rl;
    short8 af0 = *(const short8*)&Vs[d2r*64 + ((g ^ (d2r & 7)) << 3)];
    short8 af1 = *(const short8*)&Vs[d2r*64 + (((4+g) ^ (d2r & 7)) << 3)];
    f32x4 acc[4] = {};
    #pragma unroll
    for (int j = 0; j < 4; ++j) {
        int d1r = j*16 + rl;
        short8 b0 = *(const short8*)&Ks[d1r*64 + ((g ^ (d1r & 7)) << 3)];
        short8 b1 = *(const short8*)&Ks[d1r*64 + (((4+g) ^ (d1r & 7)) << 3)];
        acc[j] = __builtin_amdgcn_mfma_f32_16x16x32_bf16(af0, b0, acc[j], 0, 0, 0);
        acc[j] = __builtin_amdgcn_mfma_f32_16x16x32_bf16(af1, b1, acc[j], 0, 0, 0);
    }
    float* tb = Tb + ((size_t)((b*HH + h)*NC + c))*4096;
    #pragma unroll
    for (int j = 0; j < 4; ++j)
        #pragma unroll
        for (int rr = 0; rr < 4; ++rr)
            tb[(w*16 + g*4 + rr)*64 + j*16 + rl] = acc[j][rr];
}

// ---------------------------------------------------------------------------
// Suffix scan over chunks: Z_c = T_{c+1} + g64*Z_{c+1}, Z_31 = 0.
// Block = (b,h,d2-eighth). Writes bf16 Zt with d1-chunk XOR swizzle.
// ---------------------------------------------------------------------------
__global__ __launch_bounds__(256)
void suffix_scan(const float* __restrict__ Tb, u16* __restrict__ Zb)
{
    __shared__ float lds[NC*512];     // 64 KB
    const int q = blockIdx.x & 7;
    const int h = (blockIdx.x >> 3) & 15;
    const int b = blockIdx.x >> 7;
    const float l2g = log2f(1.f - exp2f(-5.f - (float)h));
    const float g64 = exp2f(l2g * 64.f);
    const float* tb = Tb + ((size_t)((b*HH + h)*NC))*4096 + q*512;
    u16* zb = Zb + ((size_t)((b*HH + h)*NC))*4096;
    const int tid = threadIdx.x;
    #pragma unroll
    for (int k = 0; k < 16; ++k) {
        int i4 = tid + k*256;
        int c = i4 >> 7, r = i4 & 127;
        *(float4*)&lds[c*512 + r*4] = *(const float4*)(tb + (size_t)c*4096 + r*4);
    }
    __syncthreads();
    int e0 = tid*2;
    int d2l = e0 >> 6, d1 = e0 & 63;
    int d2 = q*8 + d2l;
    int pos = d2*64 + (((d1>>3) ^ (d2 & 7)) << 3) + (d1 & 7);
    *(u32*)(zb + (size_t)31*4096 + pos) = 0u;
    float z0 = 0.f, z1 = 0.f;
    for (int c = 30; c >= 0; --c) {
        z0 = lds[(c+1)*512 + e0]     + g64*z0;
        z1 = lds[(c+1)*512 + e0 + 1] + g64*z1;
        u32 pk = (u32)f2bf(z0) | ((u32)f2bf(z1) << 16);
        *(u32*)(zb + (size_t)c*4096 + pos) = pk;
    }
}

// ---------------------------------------------------------------------------
// Output: per chunk c:
//   R = (QK^T/8 ∘ mask_diag) V  +  0.125*gamma^(64-m̂) * Q · Z_c
// ---------------------------------------------------------------------------
__global__ __launch_bounds__(256)
void ret_out(const u16* __restrict__ Q, const u16* __restrict__ K,
             const u16* __restrict__ VT, const u16* __restrict__ Zb,
             float* __restrict__ R)
{
    __shared__ u16 Qs[64*64], Ks[64*64], Vs[64*64], Zs[64*64], Ss[64*64];
    const int tid = threadIdx.x, w = tid >> 6, lane = tid & 63;
    const int g = lane >> 4, rl = lane & 15;
    const int c = blockIdx.x, h = blockIdx.y, b = blockIdx.z;
    const int m0 = c*64;
    const float l2g = log2f(1.f - exp2f(-5.f - (float)h));
    const size_t vrow = (size_t)((b*HH + h)*HDD);
    const u16* zc = Zb + ((size_t)((b*HH + h)*NC + c))*4096;
    {
        int cc = tid, r = cc >> 3, ch = cc & 7;
        gload16(Q  + (size_t)(b*TT + m0 + r)*EE + h*HDD + ch*8, &Qs[cc*8]);
        gload16(K  + (size_t)(b*TT + m0 + r)*EE + h*HDD + ch*8, &Ks[cc*8]);
        gload16(VT + (vrow + r)*TT + m0 + ch*8, &Vs[cc*8]);
        gload16(zc + cc*8, &Zs[cc*8]);
        cc = tid + 256; r = cc >> 3; ch = cc & 7;
        gload16(Q  + (size_t)(b*TT + m0 + r)*EE + h*HDD + ch*8, &Qs[cc*8]);
        gload16(K  + (size_t)(b*TT + m0 + r)*EE + h*HDD + ch*8, &Ks[cc*8]);
        gload16(VT + (vrow + r)*TT + m0 + ch*8, &Vs[cc*8]);
        gload16(zc + cc*8, &Zs[cc*8]);
    }
    __syncthreads();
    const int mr = w*16 + rl;
    short8 qf[2];
    qf[0] = *(const short8*)&Qs[mr*64 + ((g ^ (rl & 7)) << 3)];
    qf[1] = *(const short8*)&Qs[mr*64 + (((4+g) ^ (rl & 7)) << 3)];
    // QK^T (diagonal tile)
    f32x4 sacc[4] = {};
    #pragma unroll
    for (int j = 0; j < 4; ++j) {
        int n = j*16 + rl;
        short8 k0 = *(const short8*)&Ks[n*64 + ((g ^ (n & 7)) << 3)];
        short8 k1 = *(const short8*)&Ks[n*64 + (((4+g) ^ (n & 7)) << 3)];
        sacc[j] = __builtin_amdgcn_mfma_f32_16x16x32_bf16(qf[0], k0, sacc[j], 0, 0, 0);
        sacc[j] = __builtin_amdgcn_mfma_f32_16x16x32_bf16(qf[1], k1, sacc[j], 0, 0, 0);
    }
    // factored decay: w(m,n) = 0.125*gamma^(n̂)*gamma^(-m̂), n̂>=m̂ only
    float pn[4], pmv[4];
    #pragma unroll
    for (int j = 0; j < 4; ++j) pn[j] = exp2f(l2g * (float)(j*16 + rl));
    #pragma unroll
    for (int rr = 0; rr < 4; ++rr) pmv[rr] = exp2f(-l2g * (float)(w*16 + g*4 + rr));
    #pragma unroll
    for (int j = 0; j < 4; ++j) {
        int nl = j*16 + rl;
        #pragma unroll
        for (int rr = 0; rr < 4; ++rr) {
            int ml = w*16 + g*4 + rr;
            float wgt = (nl >= ml) ? 0.125f * pn[j] * pmv[rr] : 0.f;
            Ss[ml*64 + (((nl>>3) ^ (ml & 7)) << 3) + (nl & 7)] = f2bf(sacc[j][rr] * wgt);
        }
    }
    asm volatile("s_waitcnt lgkmcnt(0)" ::: "memory");  // wave-private S rows
    // PV (intra) + QZ (inter)
    f32x4 oacc[4] = {}, zacc[4] = {};
    #pragma unroll
    for (int s = 0; s < 2; ++s) {
        short8 sf = *(const short8*)&Ss[mr*64 + (((s*4 + g) ^ (rl & 7)) << 3)];
        #pragma unroll
        for (int j = 0; j < 4; ++j) {
            int d = j*16 + rl;
            short8 vf = *(const short8*)&Vs[d*64 + (((s*4 + g) ^ (d & 7)) << 3)];
            oacc[j] = __builtin_amdgcn_mfma_f32_16x16x32_bf16(sf, vf, oacc[j], 0, 0, 0);
            short8 zf = *(const short8*)&Zs[d*64 + (((s*4 + g) ^ (d & 7)) << 3)];
            zacc[j] = __builtin_amdgcn_mfma_f32_16x16x32_bf16(qf[s], zf, zacc[j], 0, 0, 0);
        }
    }
    const float g64 = exp2f(l2g * 64.f);
    #pragma unroll
    for (int j = 0; j < 4; ++j)
        #pragma unroll
        for (int rr = 0; rr < 4; ++rr) {
            int m_g = m0 + w*16 + g*4 + rr;
            float rs = 0.125f * g64 * pmv[rr];
            R[(size_t)(b*TT + m_g)*EE + h*HDD + j*16 + rl] = oacc[j][rr] + rs*zacc[j][rr];
        }
}

// ---------------------------------------------------------------------------
__global__ __launch_bounds__(256)
void gn_partial(const float* __restrict__ R, float* __restrict__ part)
{
    int bid = blockIdx.x;
    int bh = bid >> 4, seg = bid & 15;
    int b = bh >> 4, h = bh & 15;
    const float* base = R + (size_t)(b*TT + seg*128)*EE + h*HDD;
    float s = 0.f, sq = 0.f;
    #pragma unroll
    for (int k = 0; k < 8; ++k) {
        int i4 = threadIdx.x + 256*k;
        int t = i4 >> 4, dq = i4 & 15;
        float4 v = *(const float4*)(base + (size_t)t*EE + dq*4);
        s  += v.x + v.y + v.z + v.w;
        sq += v.x*v.x + v.y*v.y + v.z*v.z + v.w*v.w;
    }
    #pragma unroll
    for (int off = 32; off; off >>= 1) { s += __shfl_down(s, off, 64); sq += __shfl_down(sq, off, 64); }
    __shared__ float ls[4], lq[4];
    int lane = threadIdx.x & 63, wv = threadIdx.x >> 6;
    if (lane == 0) { ls[wv] = s; lq[wv] = sq; }
    __syncthreads();
    if (threadIdx.x == 0) {
        part[2*bid]   = ls[0]+ls[1]+ls[2]+ls[3];
        part[2*bid+1] = lq[0]+lq[1]+lq[2]+lq[3];
    }
}

__global__ void gn_finalize(const float* __restrict__ part, float* __restrict__ stats)
{
    int bh = threadIdx.x;
    if (bh < 32) {
        float s = 0.f, sq = 0.f;
        #pragma unroll
        for (int k = 0; k < 16; ++k) { s += part[2*(bh*16+k)]; sq += part[2*(bh*16+k)+1]; }
        const float inv = 1.f / (float)(TT*HDD);
        float mu = s * inv;
        float var = sq * inv - mu*mu;
        stats[2*bh]   = mu;
        stats[2*bh+1] = rsqrtf(var + 1e-5f);
    }
}

// ---------------------------------------------------------------------------
__global__ __launch_bounds__(256)
void zgate(const u16* __restrict__ G, const float* __restrict__ R,
           const float* __restrict__ stats, const float* __restrict__ gw,
           const float* __restrict__ gb, u16* __restrict__ Z)
{
    int ci = blockIdx.x*256 + threadIdx.x;
    int row = ci >> 7;
    int c = ci & 127;
    int e0 = c*8;
    int b = row >> 11;
    int bh = b*HH + (e0 >> 6);
    float mu = stats[2*bh], rs = stats[2*bh+1];
    short8 gv = *(const short8*)(G + (size_t)row*EE + e0);
    const u16* gu = (const u16*)&gv;
    const float* rp = R + (size_t)row*EE + e0;
    float4 r0 = *(const float4*)rp, r1 = *(const float4*)(rp+4);
    float rr[8] = {r0.x,r0.y,r0.z,r0.w,r1.x,r1.y,r1.z,r1.w};
    short8 ov; u16* o = (u16*)&ov;
    #pragma unroll
    for (int q = 0; q < 8; ++q) {
        float gvf = bf2f(gu[q]);
        float gate = gvf / (1.f + __expf(-gvf));
        float nv = (rr[q] - mu)*rs*gw[e0+q] + gb[e0+q];
        o[q] = f2bf(gate*nv);
    }
    int pc = (c & ~3) | ((c & 3) ^ ((row >> 1) & 3));
    *(short8*)(Z + (size_t)row*EE + pc*8) = ov;
}

// ---------------------------------------------------------------------------
extern "C" void kernel_launch(void* const* d_in, const int* in_sizes, int n_in,
                              void* d_out, int out_size, void* d_ws, size_t ws_size,
                              hipStream_t stream)
{
    const float* x  = (const float*)d_in[0];
    const float* Wq = (const float*)d_in[1];
    const float* bq = (const float*)d_in[2];
    const float* Wk = (const float*)d_in[3];
    const float* bk = (const float*)d_in[4];
    const float* Wv = (const float*)d_in[5];
    const float* bv = (const float*)d_in[6];
    const float* Wg = (const float*)d_in[7];
    const float* bg = (const float*)d_in[8];
    const float* Wo = (const float*)d_in[9];
    const float* bo = (const float*)d_in[10];
    const float* gw = (const float*)d_in[11];
    const float* gb = (const float*)d_in[12];
    float* out = (float*)d_out;

    char* p = (char*)d_ws;
    u16* xb  = (u16*)p;              p += (size_t)8<<20;   // x bf16 -> Zbuf -> ZGb
    u16* Wqb = (u16*)p;              p += (size_t)2<<20;
    u16* Wkb = (u16*)p;              p += (size_t)2<<20;
    u16* Wvb = (u16*)p;              p += (size_t)2<<20;
    u16* Wgb = (u16*)p;              p += (size_t)2<<20;
    u16* Wob = (u16*)p;              p += (size_t)2<<20;
    u16* Qb  = (u16*)p;              p += (size_t)8<<20;
    u16* Kb  = (u16*)p;              p += (size_t)8<<20;
    u16* Vb  = (u16*)p;              p += (size_t)8<<20;
    u16* Gb  = (u16*)p;              p += (size_t)8<<20;
    u16* VTb = (u16*)p;              p += (size_t)8<<20;
    u16* KTb = (u16*)p;              p += (size_t)8<<20;
    float* TbRb  = (float*)p;        p += (size_t)16<<20;  // Tb (chunk states) -> Rb
    float* part  = (float*)p;        p += 4096;
    float* stats = (float*)p;        p += 256;
    float* ctab  = (float*)p;        p += (size_t)65536*4;
    float* stab  = (float*)p;        p += (size_t)65536*4;
    u16* Zbuf = xb;                  // x dead after QKVG
    float* Tb = TbRb;
    float* Rb = TbRb;                // ret_out writes after scan reads
    u16* ZGb = xb;                   // zgate output (after ret_out)

    cvt_swz<<<dim3(2048,1,6), 256, 0, stream>>>(x, Wq, Wk, Wv, Wg, Wo,
                                                xb, Wqb, Wkb, Wvb, Wgb, Wob);
    trig_tab<<<256, 256, 0, stream>>>(ctab, stab);
    gemm_qkvg<<<dim3(8,32,4), 256, 0, stream>>>(xb, Wqb, Wkb, Wvb, Wgb,
                                                bq, bk, bv, bg, Qb, Kb, Vb, Gb);
    rope_swz<<<dim3(2048,1,2), 256, 0, stream>>>(Qb, Kb, ctab, stab);
    transV<<<dim3(32,16,2), 256, 0, stream>>>(Vb, VTb);
    transK<<<dim3(32,16,2), 256, 0, stream>>>(Kb, KTb);
    chunk_state<<<dim3(32,16,2), 256, 0, stream>>>(KTb, VTb, Tb);
    suffix_scan<<<256, 256, 0, stream>>>(Tb, Zbuf);
    ret_out<<<dim3(32,16,2), 256, 0, stream>>>(Qb, Kb, VTb, Zbuf, Rb);
    gn_partial<<<512, 256, 0, stream>>>(Rb, part);
    gn_finalize<<<1, 64, 0, stream>>>(part, stats);
    zgate<<<2048, 256, 0, stream>>>(Gb, Rb, stats, gw, gb, ZGb);
    gemm_out<<<dim3(8,32,1), 256, 0, stream>>>(ZGb, Wob, bo, out);
}